// Round 6
// baseline (248.985 us; speedup 1.0000x reference)
//
#include <hip/hip_runtime.h>

#define N_NODES 50000
#define N_EDGES 250000
#define N_GRAPHS 512
#define F_IN 32
#define F_EDGE 16
#define LATENT 32
#define EMBED 128
#define DT 64                              // dst nodes owned per block
#define NB ((N_NODES + DT - 1) / DT)       // 782 dst bins / blocks
#define EC 128                             // edges per chunk
#define KW 1056                            // W2T row length: 1024 + 32 (b2 fold)
#define HS_STRIDE 36                       // Hs2 row stride in dwords (16B aligned)
#define AGG_S 33                           // LDS agg row stride (bank spread)

typedef unsigned short ushort;
typedef unsigned int uint;
typedef _Float16 half8v __attribute__((ext_vector_type(8)));
typedef _Float16 half2v __attribute__((ext_vector_type(2)));
typedef __attribute__((ext_vector_type(4))) float f32x4;

union UH8 { half8v h8; half2v h2[4]; ushort u[8]; uint q[4]; };
union UH2 { half2v h2; uint q; };

__device__ inline ushort f2h_bits(float f) {
    _Float16 h = (_Float16)f;
    return *reinterpret_cast<ushort*>(&h);
}

// ---------------- prep: zero deg/pool/pcnt + x->f16 + W2T(f16) [32 l][1056 kk] ----------------
__global__ void prep_kernel(const float* __restrict__ x, const float* __restrict__ W2,
                            const float* __restrict__ b2, ushort* __restrict__ xh,
                            ushort* __restrict__ W2T, int* __restrict__ deg,
                            float* __restrict__ pool, float* __restrict__ pcnt) {
    int i = blockIdx.x * blockDim.x + threadIdx.x;
    if (i < (N_NODES * F_IN) / 4) {
        float4 v = ((const float4*)x)[i];
        union { ushort u[4]; uint2 q; } pk;
        pk.u[0] = f2h_bits(v.x); pk.u[1] = f2h_bits(v.y);
        pk.u[2] = f2h_bits(v.z); pk.u[3] = f2h_bits(v.w);
        ((uint2*)xh)[i] = pk.q;
    }
    if (i < 32 * 1024) {
        int kk = i >> 5, l = i & 31;
        W2T[l * KW + kk] = f2h_bits(W2[i]);   // coalesced read
    }
    if (i < 1024) {
        int f = i >> 5, l = i & 31;
        W2T[l * KW + 1024 + f] = f2h_bits(b2[i]);
    }
    if (i < NB) deg[i] = 0;
    if (i < N_GRAPHS * LATENT) pool[i] = 0.f;
    if (i < N_GRAPHS) pcnt[i] = 0.f;
}

// ---------------- dst-binned CSR build ----------------
__global__ void hist_kernel(const int* __restrict__ ei, int* __restrict__ deg) {
    int e = blockIdx.x * blockDim.x + threadIdx.x;
    if (e < N_EDGES) atomicAdd(&deg[ei[N_EDGES + e] / DT], 1);
}

__global__ __launch_bounds__(1024) void scan_kernel(const int* __restrict__ deg,
                                                    int* __restrict__ off,
                                                    int* __restrict__ cursor) {
    __shared__ int wsum[16];
    int t = threadIdx.x;
    int d = (t < NB) ? deg[t] : 0;
    int lane = t & 63, wid = t >> 6;
    int inc = d;
    #pragma unroll
    for (int s = 1; s < 64; s <<= 1) {
        int o = __shfl_up(inc, s);
        if (lane >= s) inc += o;
    }
    if (lane == 63) wsum[wid] = inc;
    __syncthreads();
    if (t < 16) {
        int w = wsum[t];
        int winc = w;
        #pragma unroll
        for (int s = 1; s < 16; s <<= 1) {
            int o = __shfl_up(winc, s);
            if (t >= s) winc += o;
        }
        wsum[t] = winc - w;  // exclusive wave offset
    }
    __syncthreads();
    int base = wsum[wid] + (inc - d);  // exclusive prefix
    if (t < NB) { off[t] = base; cursor[t] = base; }
    if (t == 1023) off[NB] = base + d;  // == N_EDGES
}

__global__ void scatter_kernel(const int* __restrict__ ei, int* __restrict__ cursor,
                               int* __restrict__ csr) {
    int e = blockIdx.x * blockDim.x + threadIdx.x;
    if (e < N_EDGES) {
        int p = atomicAdd(&cursor[ei[N_EDGES + e] / DT], 1);
        csr[p] = e;
    }
}

// ---------------- fused edge-MFMA + node update + pool kernel ----------------
// Block owns dst nodes [v0, v0+DT). For its in-edges (chunks of EC):
//   MSG[e,:] = G[e,:] @ W2T^T  with  G[e,k*32+f] = h[e,k]*x[src_e,f], G[e,1024+f] = x[src_e,f]
// accumulated into LDS aggL[dst-v0][l] via ds_add. Then node update + mean-pool.
__global__ __launch_bounds__(256) void edge_mfma_kernel(
    const ushort* __restrict__ xh, const int* __restrict__ ei,
    const float* __restrict__ ea, const float* __restrict__ W1,
    const float* __restrict__ b1, const ushort* __restrict__ W2T,
    const int* __restrict__ off, const int* __restrict__ csr,
    const float* __restrict__ x, const float* __restrict__ root,
    const float* __restrict__ cbias, const int* __restrict__ batch,
    float* __restrict__ pool, float* __restrict__ pcnt)
{
    __shared__ __attribute__((aligned(16))) uint Hs2[EC * HS_STRIDE]; // {h,h} f16, 18KB
    __shared__ __attribute__((aligned(16))) ushort W2q[32 * 256];     // 16KB; row=j, swz ^((j&7)<<4)
    __shared__ float aggL[DT * AGG_S];                                // 8.25KB

    const int t = threadIdx.x;
    const int v0 = blockIdx.x * DT;
    const int wv = t >> 6, lane = t & 63;
    const int g = lane >> 4, j16 = lane & 15;
    const int estart = off[blockIdx.x];
    const int eend = off[blockIdx.x + 1];

    for (int i = t; i < DT * AGG_S; i += 256) aggL[i] = 0.f;

    // ---- loop-invariant fragments: W1 (K-padded), b1, b2-extension B
    UH8 bw[2];
    #pragma unroll
    for (int nt = 0; nt < 2; ++nt) {
        #pragma unroll
        for (int b = 0; b < 8; ++b) {
            float w = (g < 2) ? W1[(8 * g + b) * LATENT + nt * 16 + j16] : 0.f;
            bw[nt].u[b] = f2h_bits(w);
        }
    }
    float b1v[2] = { b1[j16], b1[16 + j16] };
    UH8 bx0, bx1;
    *(uint4*)bx0.q = *(const uint4*)(W2T + (size_t)j16 * KW + 1024 + 8 * g);
    *(uint4*)bx1.q = *(const uint4*)(W2T + (size_t)(16 + j16) * KW + 1024 + 8 * g);

    __syncthreads();

    for (int cs = estart; cs < eend; cs += EC) {
        int nE = eend - cs; if (nE > EC) nE = EC;

        // ---- H = relu(ea @ W1 + b1) via K-padded f16 MFMA
        #pragma unroll
        for (int mt = 0; mt < 2; ++mt) {
            int mtg = 2 * wv + mt;
            int rowA = mtg * 16 + j16;
            int p = cs + rowA; if (p >= eend) p = eend - 1;
            int e = csr[p];
            UH8 ae;
            if (g < 2) {
                const float4* pp = (const float4*)(ea + (size_t)e * F_EDGE + 8 * g);
                float4 va = pp[0], vb = pp[1];
                ae.u[0] = f2h_bits(va.x); ae.u[1] = f2h_bits(va.y);
                ae.u[2] = f2h_bits(va.z); ae.u[3] = f2h_bits(va.w);
                ae.u[4] = f2h_bits(vb.x); ae.u[5] = f2h_bits(vb.y);
                ae.u[6] = f2h_bits(vb.z); ae.u[7] = f2h_bits(vb.w);
            } else {
                ae.q[0] = 0; ae.q[1] = 0; ae.q[2] = 0; ae.q[3] = 0;
            }
            #pragma unroll
            for (int nt = 0; nt < 2; ++nt) {
                f32x4 hacc = (f32x4){0.f, 0.f, 0.f, 0.f};
                hacc = __builtin_amdgcn_mfma_f32_16x16x32_f16(ae.h8, bw[nt].h8, hacc, 0, 0, 0);
                #pragma unroll
                for (int v = 0; v < 4; ++v) {
                    int rowD = mtg * 16 + 4 * g + v;
                    int col = nt * 16 + j16;
                    float hval = fmaxf(hacc[v] + b1v[nt], 0.f);
                    uint hb = (uint)f2h_bits(hval);
                    Hs2[rowD * HS_STRIDE + col] = hb * 0x10001u;  // packed {h,h}
                }
            }
        }
        if (t < EC) Hs2[t * HS_STRIDE + 32] = 0x3C003C00u;  // b2 row: h == 1.0

        // ---- xh fragments (reused across all K)
        f32x4 acc[2][2];
        #pragma unroll
        for (int a = 0; a < 2; ++a)
            #pragma unroll
            for (int b = 0; b < 2; ++b) acc[a][b] = (f32x4){0.f, 0.f, 0.f, 0.f};

        UH8 xf[2];
        int myrow[2];
        #pragma unroll
        for (int mt = 0; mt < 2; ++mt) {
            int row = (2 * wv + mt) * 16 + j16;
            myrow[mt] = row;
            int p = cs + row; if (p >= eend) p = eend - 1;
            int src = ei[csr[p]];
            uint4 raw = *(const uint4*)(xh + (size_t)src * F_IN + 8 * g);
            xf[mt].q[0] = raw.x; xf[mt].q[1] = raw.y; xf[mt].q[2] = raw.z; xf[mt].q[3] = raw.w;
        }

        // ---- b2-extension K-step: A = x fragment (h == 1)
        #pragma unroll
        for (int mt = 0; mt < 2; ++mt) {
            acc[mt][0] = __builtin_amdgcn_mfma_f32_16x16x32_f16(xf[mt].h8, bx0.h8, acc[mt][0], 0, 0, 0);
            acc[mt][1] = __builtin_amdgcn_mfma_f32_16x16x32_f16(xf[mt].h8, bx1.h8, acc[mt][1], 0, 0, 0);
        }

        __syncthreads();  // Hs2 visible

        // ---- K loop: 4 quarters of 256 kk, W2q staged per quarter (XOR-swizzled)
        for (int q = 0; q < 4; ++q) {
            if (q) __syncthreads();
            #pragma unroll
            for (int c = 0; c < 4; ++c) {
                int ch = c * 256 + t;
                int lbyte = ch * 16;
                int jrow = lbyte >> 9;
                int offb = lbyte & 511;
                uint4 val = *(const uint4*)((const char*)W2T + (size_t)jrow * (KW * 2) + q * 512 + offb);
                *(uint4*)((char*)W2q + jrow * 512 + (offb ^ ((jrow & 7) << 4))) = val;
            }
            __syncthreads();

            uint hb[2][8];
            #pragma unroll
            for (int mt = 0; mt < 2; ++mt) {
                const uint* hp = Hs2 + myrow[mt] * HS_STRIDE + q * 8;
                uint4 a = *(const uint4*)hp;
                uint4 b = *(const uint4*)(hp + 4);
                hb[mt][0] = a.x; hb[mt][1] = a.y; hb[mt][2] = a.z; hb[mt][3] = a.w;
                hb[mt][4] = b.x; hb[mt][5] = b.y; hb[mt][6] = b.z; hb[mt][7] = b.w;
            }

            #pragma unroll
            for (int kst = 0; kst < 8; ++kst) {
                int kb = kst * 64 + g * 16;
                UH8 bf0, bf1;
                *(uint4*)bf0.q = *(const uint4*)((const char*)W2q + j16 * 512 + (kb ^ ((j16 & 7) << 4)));
                *(uint4*)bf1.q = *(const uint4*)((const char*)W2q + (16 + j16) * 512 + (kb ^ ((j16 & 7) << 4)));
                #pragma unroll
                for (int mt = 0; mt < 2; ++mt) {
                    UH2 h2; h2.q = hb[mt][kst];
                    UH8 af;
                    #pragma unroll
                    for (int p = 0; p < 4; ++p) af.h2[p] = h2.h2 * xf[mt].h2[p];  // v_pk_mul_f16
                    acc[mt][0] = __builtin_amdgcn_mfma_f32_16x16x32_f16(af.h8, bf0.h8, acc[mt][0], 0, 0, 0);
                    acc[mt][1] = __builtin_amdgcn_mfma_f32_16x16x32_f16(af.h8, bf1.h8, acc[mt][1], 0, 0, 0);
                }
            }
        }

        // ---- scatter messages into LDS accumulator (ds_add_f32)
        #pragma unroll
        for (int mt = 0; mt < 2; ++mt) {
            int rowb = (2 * wv + mt) * 16 + 4 * g;
            #pragma unroll
            for (int v = 0; v < 4; ++v) {
                int row = rowb + v;
                if (row < nE) {
                    int e = csr[cs + row];
                    int n = ei[N_EDGES + e] - v0;
                    atomicAdd(&aggL[n * AGG_S + j16],      acc[mt][0][v]);
                    atomicAdd(&aggL[n * AGG_S + 16 + j16], acc[mt][1][v]);
                }
            }
        }
        __syncthreads();  // ds_adds done; Hs2/W2q safe to overwrite next chunk
    }

    // ---- node update + global mean pool (batch sorted -> run-length flush)
    {
        int l = t & 31;
        int stripe = t >> 5;               // 8 stripes x 8 nodes = DT
        int vb = v0 + stripe * 8;
        float rc[F_IN];
        #pragma unroll
        for (int f = 0; f < F_IN; ++f) rc[f] = root[f * LATENT + l];
        float cbl = cbias[l];

        float sum = 0.f, cnt = 0.f;
        int gcur = -1;
        for (int i = 0; i < 8; ++i) {
            int v = vb + i;
            if (v >= N_NODES) break;
            int gr = batch[v];
            if (gr != gcur) {
                if (gcur >= 0) {
                    atomicAdd(&pool[gcur * LATENT + l], sum);
                    if (l == 0) atomicAdd(&pcnt[gcur], cnt);
                }
                gcur = gr; sum = 0.f; cnt = 0.f;
            }
            float xv = x[(size_t)v * F_IN + l];   // coalesced per 32-lane group
            float a = aggL[(v - v0) * AGG_S + l] + cbl;
            #pragma unroll
            for (int f = 0; f < F_IN; ++f) {
                float xfv = __shfl(xv, (t & 32) | f);
                a += xfv * rc[f];
            }
            sum += fmaxf(a, 0.f);
            cnt += 1.f;
        }
        if (gcur >= 0) {
            atomicAdd(&pool[gcur * LATENT + l], sum);
            if (l == 0) atomicAdd(&pcnt[gcur], cnt);
        }
    }
}

// ---------------- final FC ----------------
__global__ void final_kernel(const float* __restrict__ pool, const float* __restrict__ pcnt,
                             const float* __restrict__ fcw, const float* __restrict__ fcb,
                             float* __restrict__ out)
{
    int t = blockIdx.x * blockDim.x + threadIdx.x;
    int gr = t >> 7, j = t & 127;
    if (gr >= N_GRAPHS) return;
    float inv = 1.0f / fmaxf(pcnt[gr], 1.0f);
    float o = fcb[j];
    #pragma unroll 8
    for (int l = 0; l < LATENT; ++l) {
        float pv = fmaxf(pool[gr * LATENT + l] * inv, 0.0f);
        o += pv * fcw[l * EMBED + j];
    }
    out[gr * EMBED + j] = o;
}

extern "C" void kernel_launch(void* const* d_in, const int* in_sizes, int n_in,
                              void* d_out, int out_size, void* d_ws, size_t ws_size,
                              hipStream_t stream)
{
    const float* x     = (const float*)d_in[0];
    const int*   ei    = (const int*)d_in[1];
    const float* ea    = (const float*)d_in[2];
    const int*   batch = (const int*)d_in[3];
    const float* W1    = (const float*)d_in[4];
    const float* b1    = (const float*)d_in[5];
    const float* W2    = (const float*)d_in[6];
    const float* b2    = (const float*)d_in[7];
    const float* root  = (const float*)d_in[8];
    const float* cb    = (const float*)d_in[9];
    const float* fcw   = (const float*)d_in[10];
    const float* fcb   = (const float*)d_in[11];
    float* out = (float*)d_out;

    char* w = (char*)d_ws;
    auto alloc = [&](size_t bytes) {
        char* p = w;
        w += (bytes + 255) & ~size_t(255);
        return p;
    };
    ushort* W2T    = (ushort*)alloc((size_t)32 * KW * 2);
    ushort* xh     = (ushort*)alloc((size_t)N_NODES * F_IN * 2);
    int*    deg    = (int*)alloc(NB * 4);
    int*    off    = (int*)alloc((NB + 1) * 4);
    int*    cursor = (int*)alloc(NB * 4);
    int*    csr    = (int*)alloc(N_EDGES * 4);
    float*  pool   = (float*)alloc(N_GRAPHS * LATENT * 4);
    float*  pcnt   = (float*)alloc(N_GRAPHS * 4);

    prep_kernel<<<1563, 256, 0, stream>>>(x, W2, b2, xh, W2T, deg, pool, pcnt);
    hist_kernel<<<(N_EDGES + 255) / 256, 256, 0, stream>>>(ei, deg);
    scan_kernel<<<1, 1024, 0, stream>>>(deg, off, cursor);
    scatter_kernel<<<(N_EDGES + 255) / 256, 256, 0, stream>>>(ei, cursor, csr);
    edge_mfma_kernel<<<NB, 256, 0, stream>>>(xh, ei, ea, W1, b1, W2T, off, csr,
                                             x, root, cb, batch, pool, pcnt);
    final_kernel<<<(N_GRAPHS * EMBED + 255) / 256, 256, 0, stream>>>(pool, pcnt, fcw, fcb, out);
}

// Round 7
// 77.875 us; speedup vs baseline: 3.1972x; 3.1972x over previous
//
#include <hip/hip_runtime.h>

#define N_NODES 50000
#define N_EDGES 250000
#define N_GRAPHS 512
#define F_IN 32
#define F_EDGE 16
#define LATENT 32
#define EMBED 128
#define E_BLK 256
#define N_EBLK ((N_EDGES + E_BLK - 1) / E_BLK)  // 977
#define KW 1056                                  // W2T row length: 1024 + 32 (b2 fold)
#define HS_STRIDE 36                             // Hs2 row stride in dwords (16B aligned)

typedef unsigned short ushort;
typedef unsigned int uint;
typedef _Float16 half8v __attribute__((ext_vector_type(8)));
typedef _Float16 half2v __attribute__((ext_vector_type(2)));
typedef __attribute__((ext_vector_type(4))) float f32x4;

union UH8 { half8v h8; half2v h2[4]; ushort u[8]; uint q[4]; };
union UH2 { half2v h2; uint q; };

__device__ inline ushort f2h_bits(float f) {
    _Float16 h = (_Float16)f;
    return *reinterpret_cast<ushort*>(&h);
}

// ---------------- prep: zero agg/pool + x->f16 + W2T(f16) [32 l][1056 kk] ----------------
// kk < 1024:  W2T[l][kk] = W2.flat[kk*32 + l]
// kk >= 1024: W2T[l][1024+f] = b2[f*32 + l]    (b2 folded; paired with h == 1)
__global__ void prep_kernel(const float* __restrict__ x, const float* __restrict__ W2,
                            const float* __restrict__ b2, ushort* __restrict__ xh,
                            ushort* __restrict__ W2T, float4* __restrict__ agg4,
                            float* __restrict__ pool, float* __restrict__ pcnt) {
    int i = blockIdx.x * blockDim.x + threadIdx.x;
    if (i < (N_NODES * F_IN) / 4) {
        float4 v = ((const float4*)x)[i];
        union { ushort u[4]; uint2 q; } pk;
        pk.u[0] = f2h_bits(v.x); pk.u[1] = f2h_bits(v.y);
        pk.u[2] = f2h_bits(v.z); pk.u[3] = f2h_bits(v.w);
        ((uint2*)xh)[i] = pk.q;
    }
    if (i < (N_NODES * LATENT) / 4) agg4[i] = make_float4(0.f, 0.f, 0.f, 0.f);
    if (i < 32 * 1024) {
        int kk = i >> 5, l = i & 31;
        W2T[l * KW + kk] = f2h_bits(W2[i]);   // coalesced read
    }
    if (i < 1024) {
        int f = i >> 5, l = i & 31;
        W2T[l * KW + 1024 + f] = f2h_bits(b2[i]);
    }
    if (i < N_GRAPHS * LATENT) pool[i] = 0.f;
    if (i < N_GRAPHS) pcnt[i] = 0.f;
}

// ---------------- edge kernel: MSG[E x 32] = G[E x 1056] @ W2T^T  (f16 MFMA) ----------------
// G[e, k*32+f] = h[e,k] * x[src_e, f]  (k<32) ;  G[e, 1024+f] = x[src_e, f]
// MFMA 16x16x32: A row i = lane&15, k-slot = (lane>>4)*8+b;
//                D col j = lane&15, row i = (lane>>4)*4 + reg.
// 512 threads = 8 waves; each wave owns 2 16-row M-tiles (256 edges/block).
__global__ __launch_bounds__(512) void edge_mfma_kernel(
    const ushort* __restrict__ xh, const int* __restrict__ ei,
    const float* __restrict__ ea, const float* __restrict__ W1,
    const float* __restrict__ b1, const ushort* __restrict__ W2T,
    float* __restrict__ agg)
{
    __shared__ __attribute__((aligned(16))) uint Hs2[E_BLK * HS_STRIDE]; // {h,h} f16, 36KB
    __shared__ __attribute__((aligned(16))) ushort W2q[32 * 256];        // 16KB; row=j (512B), swz ^((j&7)<<4)

    const int t = threadIdx.x;
    const int e0 = blockIdx.x * E_BLK;
    const int wv = t >> 6, lane = t & 63;
    const int g = lane >> 4, j16 = lane & 15;

    // ---- H = relu(ea @ W1 + b1) via K-padded f16 MFMA (f>=16 lanes hold zeros)
    UH8 bw[2];
    #pragma unroll
    for (int nt = 0; nt < 2; ++nt) {
        #pragma unroll
        for (int b = 0; b < 8; ++b) {
            float w = (g < 2) ? W1[(8 * g + b) * LATENT + nt * 16 + j16] : 0.f;
            bw[nt].u[b] = f2h_bits(w);
        }
    }
    float b1v[2] = { b1[j16], b1[16 + j16] };

    #pragma unroll
    for (int mt = 0; mt < 2; ++mt) {
        int mtg = 2 * wv + mt;               // 0..15
        int rowA = mtg * 16 + j16;
        int e = e0 + rowA; if (e >= N_EDGES) e = N_EDGES - 1;
        UH8 ae;
        if (g < 2) {
            const float4* p = (const float4*)(ea + (size_t)e * F_EDGE + 8 * g);
            float4 va = p[0], vb = p[1];
            ae.u[0] = f2h_bits(va.x); ae.u[1] = f2h_bits(va.y);
            ae.u[2] = f2h_bits(va.z); ae.u[3] = f2h_bits(va.w);
            ae.u[4] = f2h_bits(vb.x); ae.u[5] = f2h_bits(vb.y);
            ae.u[6] = f2h_bits(vb.z); ae.u[7] = f2h_bits(vb.w);
        } else {
            ae.q[0] = 0; ae.q[1] = 0; ae.q[2] = 0; ae.q[3] = 0;
        }
        #pragma unroll
        for (int nt = 0; nt < 2; ++nt) {
            f32x4 hacc = (f32x4){0.f, 0.f, 0.f, 0.f};
            hacc = __builtin_amdgcn_mfma_f32_16x16x32_f16(ae.h8, bw[nt].h8, hacc, 0, 0, 0);
            #pragma unroll
            for (int v = 0; v < 4; ++v) {
                int rowD = mtg * 16 + 4 * g + v;
                int col = nt * 16 + j16;
                float hval = fmaxf(hacc[v] + b1v[nt], 0.f);
                uint hb = (uint)f2h_bits(hval);
                Hs2[rowD * HS_STRIDE + col] = hb * 0x10001u;  // packed {h,h}
            }
        }
    }
    // b2-extension row: h == 1.0 for every edge (k = 32)
    if (t < E_BLK) Hs2[t * HS_STRIDE + 32] = 0x3C003C00u;

    // ---- xh fragments (f16, reused across all K): lane's 8 f-values (f = 8g+b) per M-tile
    f32x4 acc[2][2];
    #pragma unroll
    for (int a = 0; a < 2; ++a)
        #pragma unroll
        for (int b = 0; b < 2; ++b) acc[a][b] = (f32x4){0.f, 0.f, 0.f, 0.f};

    UH8 xf[2];
    int myrow[2];
    #pragma unroll
    for (int mt = 0; mt < 2; ++mt) {
        int row = (2 * wv + mt) * 16 + j16;
        myrow[mt] = row;
        int e = e0 + row; if (e >= N_EDGES) e = N_EDGES - 1;
        int src = ei[e];
        uint4 raw = *(const uint4*)(xh + (size_t)src * F_IN + 8 * g);
        xf[mt].q[0] = raw.x; xf[mt].q[1] = raw.y; xf[mt].q[2] = raw.z; xf[mt].q[3] = raw.w;
    }

    // ---- b2-extension K-step: A = x fragment directly (h == 1)
    {
        UH8 bx0, bx1;
        *(uint4*)bx0.q = *(const uint4*)(W2T + (size_t)j16 * KW + 1024 + 8 * g);
        *(uint4*)bx1.q = *(const uint4*)(W2T + (size_t)(16 + j16) * KW + 1024 + 8 * g);
        #pragma unroll
        for (int mt = 0; mt < 2; ++mt) {
            acc[mt][0] = __builtin_amdgcn_mfma_f32_16x16x32_f16(xf[mt].h8, bx0.h8, acc[mt][0], 0, 0, 0);
            acc[mt][1] = __builtin_amdgcn_mfma_f32_16x16x32_f16(xf[mt].h8, bx1.h8, acc[mt][1], 0, 0, 0);
        }
    }

    __syncthreads();  // Hs2 (incl. cross-wave b2 row) visible to all

    // ---- K loop: 4 quarters of 256 kk, W2T staged per quarter (XOR-swizzled)
    for (int q = 0; q < 4; ++q) {
        if (q) __syncthreads();
        #pragma unroll
        for (int c = 0; c < 2; ++c) {
            int ch = c * 512 + t;           // 1024 uint4 = 16KB staged by 512 threads
            int lbyte = ch * 16;
            int jrow = lbyte >> 9;
            int off = lbyte & 511;
            uint4 val = *(const uint4*)((const char*)W2T + (size_t)jrow * (KW * 2) + q * 512 + off);
            *(uint4*)((char*)W2q + jrow * 512 + (off ^ ((jrow & 7) << 4))) = val;
        }
        __syncthreads();

        // batched h2 fetch: 8 packed {h,h} per M-tile for k = q*8 .. q*8+7
        uint hb[2][8];
        #pragma unroll
        for (int mt = 0; mt < 2; ++mt) {
            const uint* hp = Hs2 + myrow[mt] * HS_STRIDE + q * 8;
            uint4 a = *(const uint4*)hp;
            uint4 b = *(const uint4*)(hp + 4);
            hb[mt][0] = a.x; hb[mt][1] = a.y; hb[mt][2] = a.z; hb[mt][3] = a.w;
            hb[mt][4] = b.x; hb[mt][5] = b.y; hb[mt][6] = b.z; hb[mt][7] = b.w;
        }

        #pragma unroll
        for (int kst = 0; kst < 8; ++kst) {
            int kb = kst * 64 + g * 16;
            UH8 bf0, bf1;
            *(uint4*)bf0.q = *(const uint4*)((const char*)W2q + j16 * 512 + (kb ^ ((j16 & 7) << 4)));
            *(uint4*)bf1.q = *(const uint4*)((const char*)W2q + (16 + j16) * 512 + (kb ^ ((j16 & 7) << 4)));
            #pragma unroll
            for (int mt = 0; mt < 2; ++mt) {
                UH2 h2; h2.q = hb[mt][kst];
                UH8 af;
                #pragma unroll
                for (int p = 0; p < 4; ++p) af.h2[p] = h2.h2 * xf[mt].h2[p];  // v_pk_mul_f16
                acc[mt][0] = __builtin_amdgcn_mfma_f32_16x16x32_f16(af.h8, bf0.h8, acc[mt][0], 0, 0, 0);
                acc[mt][1] = __builtin_amdgcn_mfma_f32_16x16x32_f16(af.h8, bf1.h8, acc[mt][1], 0, 0, 0);
            }
        }
    }

    // ---- scatter-add to agg[dst]
    #pragma unroll
    for (int mt = 0; mt < 2; ++mt) {
        int rowb = (2 * wv + mt) * 16 + 4 * g;
        #pragma unroll
        for (int v = 0; v < 4; ++v) {
            int e = e0 + rowb + v;
            if (e < N_EDGES) {
                int dst = ei[N_EDGES + e];
                atomicAdd(&agg[(size_t)dst * LATENT + j16],      acc[mt][0][v]);
                atomicAdd(&agg[(size_t)dst * LATENT + 16 + j16], acc[mt][1][v]);
            }
        }
    }
}

// ---------------- node update + global mean pool ----------------
// Lane l owns column l; each 32-lane group walks VN consecutive nodes with a running
// per-graph partial sum (batch sorted -> ~1 atomic flush per graph-run per stripe).
#define VN 8
__global__ __launch_bounds__(256) void nodepool_kernel(
    const float* __restrict__ x, const float* __restrict__ agg,
    const float* __restrict__ root, const float* __restrict__ cbias,
    const int* __restrict__ batch, float* __restrict__ pool,
    float* __restrict__ pcnt)
{
    int t = threadIdx.x;
    int l = t & 31;
    int stripe = t >> 5;  // 0..7
    int v0 = (blockIdx.x * 8 + stripe) * VN;
    float rc[F_IN];
    #pragma unroll
    for (int f = 0; f < F_IN; ++f) rc[f] = root[f * LATENT + l];
    float cbl = cbias[l];

    float sum = 0.f, cnt = 0.f;
    int gcur = -1;
    for (int i = 0; i < VN; ++i) {
        int v = v0 + i;
        if (v >= N_NODES) break;
        int g = batch[v];
        if (g != gcur) {
            if (gcur >= 0) {
                atomicAdd(&pool[gcur * LATENT + l], sum);
                if (l == 0) atomicAdd(&pcnt[gcur], cnt);
            }
            gcur = g; sum = 0.f; cnt = 0.f;
        }
        float xv = x[(size_t)v * F_IN + l];     // coalesced
        float a = agg[(size_t)v * LATENT + l] + cbl;
        #pragma unroll
        for (int f = 0; f < F_IN; ++f) {
            float xfv = __shfl(xv, (t & 32) | f);
            a += xfv * rc[f];
        }
        sum += fmaxf(a, 0.f);
        cnt += 1.f;
    }
    if (gcur >= 0) {
        atomicAdd(&pool[gcur * LATENT + l], sum);
        if (l == 0) atomicAdd(&pcnt[gcur], cnt);
    }
}

// ---------------- final FC ----------------
__global__ void final_kernel(const float* __restrict__ pool, const float* __restrict__ pcnt,
                             const float* __restrict__ fcw, const float* __restrict__ fcb,
                             float* __restrict__ out)
{
    int t = blockIdx.x * blockDim.x + threadIdx.x;
    int gr = t >> 7, j = t & 127;
    if (gr >= N_GRAPHS) return;
    float inv = 1.0f / fmaxf(pcnt[gr], 1.0f);
    float o = fcb[j];
    #pragma unroll 8
    for (int l = 0; l < LATENT; ++l) {
        float pv = fmaxf(pool[gr * LATENT + l] * inv, 0.0f);
        o += pv * fcw[l * EMBED + j];
    }
    out[gr * EMBED + j] = o;
}

extern "C" void kernel_launch(void* const* d_in, const int* in_sizes, int n_in,
                              void* d_out, int out_size, void* d_ws, size_t ws_size,
                              hipStream_t stream)
{
    const float* x     = (const float*)d_in[0];
    const int*   ei    = (const int*)d_in[1];
    const float* ea    = (const float*)d_in[2];
    const int*   batch = (const int*)d_in[3];
    const float* W1    = (const float*)d_in[4];
    const float* b1    = (const float*)d_in[5];
    const float* W2    = (const float*)d_in[6];
    const float* b2    = (const float*)d_in[7];
    const float* root  = (const float*)d_in[8];
    const float* cb    = (const float*)d_in[9];
    const float* fcw   = (const float*)d_in[10];
    const float* fcb   = (const float*)d_in[11];
    float* out = (float*)d_out;

    char* w = (char*)d_ws;
    auto alloc = [&](size_t bytes) {
        char* p = w;
        w += (bytes + 255) & ~size_t(255);
        return p;
    };
    ushort* W2T  = (ushort*)alloc((size_t)32 * KW * 2);
    ushort* xh   = (ushort*)alloc((size_t)N_NODES * F_IN * 2);
    float*  agg  = (float*)alloc((size_t)N_NODES * LATENT * 4);
    float*  pool = (float*)alloc(N_GRAPHS * LATENT * 4);
    float*  pcnt = (float*)alloc(N_GRAPHS * 4);

    prep_kernel<<<1563, 256, 0, stream>>>(x, W2, b2, xh, W2T, (float4*)agg, pool, pcnt);
    edge_mfma_kernel<<<N_EBLK, 512, 0, stream>>>(xh, ei, ea, W1, b1, W2T, agg);
    nodepool_kernel<<<(N_NODES + 8 * VN - 1) / (8 * VN), 256, 0, stream>>>(
        x, agg, root, cb, batch, pool, pcnt);
    final_kernel<<<(N_GRAPHS * EMBED + 255) / 256, 256, 0, stream>>>(pool, pcnt, fcw, fcb, out);
}

// Round 8
// 64.285 us; speedup vs baseline: 3.8732x; 1.2114x over previous
//
#include <hip/hip_runtime.h>
#include <hip/hip_fp16.h>

#define N_NODES 50000
#define N_EDGES 250000
#define N_GRAPHS 512
#define F_IN 32
#define F_EDGE 16
#define LATENT 32
#define EMBED 128
#define E_BLK 256
#define N_EBLK ((N_EDGES + E_BLK - 1) / E_BLK)  // 977
#define KW 1056                                  // W2T row length: 1024 + 32 (b2 fold)
#define HS_STRIDE 36                             // Hs2 row stride in dwords (16B aligned)

typedef unsigned short ushort;
typedef unsigned int uint;
typedef _Float16 half8v __attribute__((ext_vector_type(8)));
typedef _Float16 half2v __attribute__((ext_vector_type(2)));
typedef __attribute__((ext_vector_type(4))) float f32x4;

union UH8 { half8v h8; half2v h2[4]; ushort u[8]; uint q[4]; };
union UH2 { half2v h2; uint q; };

__device__ inline ushort f2h_bits(float f) {
    _Float16 h = (_Float16)f;
    return *reinterpret_cast<ushort*>(&h);
}

// ---------------- prep: zero agg(f16)/pool + x->f16 + W2T(f16) [32 l][1056 kk] ----------------
// kk < 1024:  W2T[l][kk] = W2.flat[kk*32 + l]
// kk >= 1024: W2T[l][1024+f] = b2[f*32 + l]    (b2 folded; paired with h == 1)
__global__ void prep_kernel(const float* __restrict__ x, const float* __restrict__ W2,
                            const float* __restrict__ b2, ushort* __restrict__ xh,
                            ushort* __restrict__ W2T, uint4* __restrict__ aggz,
                            float* __restrict__ pool, float* __restrict__ pcnt) {
    int i = blockIdx.x * blockDim.x + threadIdx.x;
    if (i < (N_NODES * F_IN) / 4) {
        float4 v = ((const float4*)x)[i];
        union { ushort u[4]; uint2 q; } pk;
        pk.u[0] = f2h_bits(v.x); pk.u[1] = f2h_bits(v.y);
        pk.u[2] = f2h_bits(v.z); pk.u[3] = f2h_bits(v.w);
        ((uint2*)xh)[i] = pk.q;
    }
    if (i < (N_NODES * LATENT * 2) / 16) aggz[i] = make_uint4(0u, 0u, 0u, 0u);  // agg f16 zeros
    if (i < 32 * 1024) {
        int kk = i >> 5, l = i & 31;
        W2T[l * KW + kk] = f2h_bits(W2[i]);   // coalesced read
    }
    if (i < 1024) {
        int f = i >> 5, l = i & 31;
        W2T[l * KW + 1024 + f] = f2h_bits(b2[i]);
    }
    if (i < N_GRAPHS * LATENT) pool[i] = 0.f;
    if (i < N_GRAPHS) pcnt[i] = 0.f;
}

// ---------------- edge kernel: MSG[E x 32] = G[E x 1056] @ W2T^T  (f16 MFMA) ----------------
// G[e, k*32+f] = h[e,k] * x[src_e, f]  (k<32) ;  G[e, 1024+f] = x[src_e, f]
// MFMA 16x16x32: A row i = lane&15, k-slot = (lane>>4)*8+b;
//                D col j = lane&15, row i = (lane>>4)*4 + reg.
// 512 threads = 8 waves; each wave owns 2 16-row M-tiles (256 edges/block).
// Scatter: packed f16 atomics (global_atomic_pk_add_f16), 2 cols per lane-atomic.
__global__ __launch_bounds__(512) void edge_mfma_kernel(
    const ushort* __restrict__ xh, const int* __restrict__ ei,
    const float* __restrict__ ea, const float* __restrict__ W1,
    const float* __restrict__ b1, const ushort* __restrict__ W2T,
    __half* __restrict__ aggh)
{
    __shared__ __attribute__((aligned(16))) uint Hs2[E_BLK * HS_STRIDE]; // {h,h} f16, 36KB
    __shared__ __attribute__((aligned(16))) ushort W2q[32 * 256];        // 16KB; row=j (512B), swz ^((j&7)<<4)

    const int t = threadIdx.x;
    const int e0 = blockIdx.x * E_BLK;
    const int wv = t >> 6, lane = t & 63;
    const int g = lane >> 4, j16 = lane & 15;

    // ---- H = relu(ea @ W1 + b1) via K-padded f16 MFMA (f>=16 lanes hold zeros)
    UH8 bw[2];
    #pragma unroll
    for (int nt = 0; nt < 2; ++nt) {
        #pragma unroll
        for (int b = 0; b < 8; ++b) {
            float w = (g < 2) ? W1[(8 * g + b) * LATENT + nt * 16 + j16] : 0.f;
            bw[nt].u[b] = f2h_bits(w);
        }
    }
    float b1v[2] = { b1[j16], b1[16 + j16] };

    #pragma unroll
    for (int mt = 0; mt < 2; ++mt) {
        int mtg = 2 * wv + mt;               // 0..15
        int rowA = mtg * 16 + j16;
        int e = e0 + rowA; if (e >= N_EDGES) e = N_EDGES - 1;
        UH8 ae;
        if (g < 2) {
            const float4* p = (const float4*)(ea + (size_t)e * F_EDGE + 8 * g);
            float4 va = p[0], vb = p[1];
            ae.u[0] = f2h_bits(va.x); ae.u[1] = f2h_bits(va.y);
            ae.u[2] = f2h_bits(va.z); ae.u[3] = f2h_bits(va.w);
            ae.u[4] = f2h_bits(vb.x); ae.u[5] = f2h_bits(vb.y);
            ae.u[6] = f2h_bits(vb.z); ae.u[7] = f2h_bits(vb.w);
        } else {
            ae.q[0] = 0; ae.q[1] = 0; ae.q[2] = 0; ae.q[3] = 0;
        }
        #pragma unroll
        for (int nt = 0; nt < 2; ++nt) {
            f32x4 hacc = (f32x4){0.f, 0.f, 0.f, 0.f};
            hacc = __builtin_amdgcn_mfma_f32_16x16x32_f16(ae.h8, bw[nt].h8, hacc, 0, 0, 0);
            #pragma unroll
            for (int v = 0; v < 4; ++v) {
                int rowD = mtg * 16 + 4 * g + v;
                int col = nt * 16 + j16;
                float hval = fmaxf(hacc[v] + b1v[nt], 0.f);
                uint hb = (uint)f2h_bits(hval);
                Hs2[rowD * HS_STRIDE + col] = hb * 0x10001u;  // packed {h,h}
            }
        }
    }
    // b2-extension row: h == 1.0 for every edge (k = 32)
    if (t < E_BLK) Hs2[t * HS_STRIDE + 32] = 0x3C003C00u;

    // ---- xh fragments (f16, reused across all K): lane's 8 f-values (f = 8g+b) per M-tile
    f32x4 acc[2][2];
    #pragma unroll
    for (int a = 0; a < 2; ++a)
        #pragma unroll
        for (int b = 0; b < 2; ++b) acc[a][b] = (f32x4){0.f, 0.f, 0.f, 0.f};

    UH8 xf[2];
    int myrow[2];
    #pragma unroll
    for (int mt = 0; mt < 2; ++mt) {
        int row = (2 * wv + mt) * 16 + j16;
        myrow[mt] = row;
        int e = e0 + row; if (e >= N_EDGES) e = N_EDGES - 1;
        int src = ei[e];
        uint4 raw = *(const uint4*)(xh + (size_t)src * F_IN + 8 * g);
        xf[mt].q[0] = raw.x; xf[mt].q[1] = raw.y; xf[mt].q[2] = raw.z; xf[mt].q[3] = raw.w;
    }

    // ---- b2-extension K-step: A = x fragment directly (h == 1)
    {
        UH8 bx0, bx1;
        *(uint4*)bx0.q = *(const uint4*)(W2T + (size_t)j16 * KW + 1024 + 8 * g);
        *(uint4*)bx1.q = *(const uint4*)(W2T + (size_t)(16 + j16) * KW + 1024 + 8 * g);
        #pragma unroll
        for (int mt = 0; mt < 2; ++mt) {
            acc[mt][0] = __builtin_amdgcn_mfma_f32_16x16x32_f16(xf[mt].h8, bx0.h8, acc[mt][0], 0, 0, 0);
            acc[mt][1] = __builtin_amdgcn_mfma_f32_16x16x32_f16(xf[mt].h8, bx1.h8, acc[mt][1], 0, 0, 0);
        }
    }

    __syncthreads();  // Hs2 (incl. cross-wave b2 row) visible to all

    // ---- K loop: 4 quarters of 256 kk, W2T staged per quarter (XOR-swizzled)
    for (int q = 0; q < 4; ++q) {
        if (q) __syncthreads();
        #pragma unroll
        for (int c = 0; c < 2; ++c) {
            int ch = c * 512 + t;           // 1024 uint4 = 16KB staged by 512 threads
            int lbyte = ch * 16;
            int jrow = lbyte >> 9;
            int off = lbyte & 511;
            uint4 val = *(const uint4*)((const char*)W2T + (size_t)jrow * (KW * 2) + q * 512 + off);
            *(uint4*)((char*)W2q + jrow * 512 + (off ^ ((jrow & 7) << 4))) = val;
        }
        __syncthreads();

        // batched h2 fetch: 8 packed {h,h} per M-tile for k = q*8 .. q*8+7
        uint hb[2][8];
        #pragma unroll
        for (int mt = 0; mt < 2; ++mt) {
            const uint* hp = Hs2 + myrow[mt] * HS_STRIDE + q * 8;
            uint4 a = *(const uint4*)hp;
            uint4 b = *(const uint4*)(hp + 4);
            hb[mt][0] = a.x; hb[mt][1] = a.y; hb[mt][2] = a.z; hb[mt][3] = a.w;
            hb[mt][4] = b.x; hb[mt][5] = b.y; hb[mt][6] = b.z; hb[mt][7] = b.w;
        }

        #pragma unroll
        for (int kst = 0; kst < 8; ++kst) {
            int kb = kst * 64 + g * 16;
            UH8 bf0, bf1;
            *(uint4*)bf0.q = *(const uint4*)((const char*)W2q + j16 * 512 + (kb ^ ((j16 & 7) << 4)));
            *(uint4*)bf1.q = *(const uint4*)((const char*)W2q + (16 + j16) * 512 + (kb ^ ((j16 & 7) << 4)));
            #pragma unroll
            for (int mt = 0; mt < 2; ++mt) {
                UH2 h2; h2.q = hb[mt][kst];
                UH8 af;
                #pragma unroll
                for (int p = 0; p < 4; ++p) af.h2[p] = h2.h2 * xf[mt].h2[p];  // v_pk_mul_f16
                acc[mt][0] = __builtin_amdgcn_mfma_f32_16x16x32_f16(af.h8, bf0.h8, acc[mt][0], 0, 0, 0);
                acc[mt][1] = __builtin_amdgcn_mfma_f32_16x16x32_f16(af.h8, bf1.h8, acc[mt][1], 0, 0, 0);
            }
        }
    }

    // ---- scatter-add to aggh[dst] with packed-f16 atomics (2 cols per lane-atomic)
    // Lane pairs (2m, 2m+1) within each 16-lane group exchange via shfl_xor(1):
    //   even lane: cols (j16, j16+1)   of low  half (acc[mt][0])
    //   odd  lane: cols (j16+15,j16+16) of high half (acc[mt][1])
    const int odd = j16 & 1;
    #pragma unroll
    for (int mt = 0; mt < 2; ++mt) {
        int rowb = (2 * wv + mt) * 16 + 4 * g;
        #pragma unroll
        for (int v = 0; v < 4; ++v) {
            int e = e0 + rowb + v;
            float a0 = acc[mt][0][v], a1 = acc[mt][1][v];
            float p0 = __shfl_xor(a0, 1);
            float p1 = __shfl_xor(a1, 1);
            if (e < N_EDGES) {
                int dst = ei[N_EDGES + e];
                __half2 hv = odd ? __floats2half2_rn(p1, a1) : __floats2half2_rn(a0, p0);
                int col = odd ? (15 + j16) : j16;
                unsafeAtomicAdd((__half2*)(aggh + (size_t)dst * LATENT + col), hv);
            }
        }
    }
}

// ---------------- node update + global mean pool ----------------
// Lane l owns column l; each 32-lane group walks VN consecutive nodes with a running
// per-graph partial sum (batch sorted -> ~1 atomic flush per graph-run per stripe).
#define VN 8
__global__ __launch_bounds__(256) void nodepool_kernel(
    const float* __restrict__ x, const __half* __restrict__ aggh,
    const float* __restrict__ root, const float* __restrict__ cbias,
    const int* __restrict__ batch, float* __restrict__ pool,
    float* __restrict__ pcnt)
{
    int t = threadIdx.x;
    int l = t & 31;
    int stripe = t >> 5;  // 0..7
    int v0 = (blockIdx.x * 8 + stripe) * VN;
    float rc[F_IN];
    #pragma unroll
    for (int f = 0; f < F_IN; ++f) rc[f] = root[f * LATENT + l];
    float cbl = cbias[l];

    float sum = 0.f, cnt = 0.f;
    int gcur = -1;
    for (int i = 0; i < VN; ++i) {
        int v = v0 + i;
        if (v >= N_NODES) break;
        int g = batch[v];
        if (g != gcur) {
            if (gcur >= 0) {
                atomicAdd(&pool[gcur * LATENT + l], sum);
                if (l == 0) atomicAdd(&pcnt[gcur], cnt);
            }
            gcur = g; sum = 0.f; cnt = 0.f;
        }
        float xv = x[(size_t)v * F_IN + l];     // coalesced
        float a = __half2float(aggh[(size_t)v * LATENT + l]) + cbl;
        #pragma unroll
        for (int f = 0; f < F_IN; ++f) {
            float xfv = __shfl(xv, (t & 32) | f);
            a += xfv * rc[f];
        }
        sum += fmaxf(a, 0.f);
        cnt += 1.f;
    }
    if (gcur >= 0) {
        atomicAdd(&pool[gcur * LATENT + l], sum);
        if (l == 0) atomicAdd(&pcnt[gcur], cnt);
    }
}

// ---------------- final FC ----------------
__global__ void final_kernel(const float* __restrict__ pool, const float* __restrict__ pcnt,
                             const float* __restrict__ fcw, const float* __restrict__ fcb,
                             float* __restrict__ out)
{
    int t = blockIdx.x * blockDim.x + threadIdx.x;
    int gr = t >> 7, j = t & 127;
    if (gr >= N_GRAPHS) return;
    float inv = 1.0f / fmaxf(pcnt[gr], 1.0f);
    float o = fcb[j];
    #pragma unroll 8
    for (int l = 0; l < LATENT; ++l) {
        float pv = fmaxf(pool[gr * LATENT + l] * inv, 0.0f);
        o += pv * fcw[l * EMBED + j];
    }
    out[gr * EMBED + j] = o;
}

extern "C" void kernel_launch(void* const* d_in, const int* in_sizes, int n_in,
                              void* d_out, int out_size, void* d_ws, size_t ws_size,
                              hipStream_t stream)
{
    const float* x     = (const float*)d_in[0];
    const int*   ei    = (const int*)d_in[1];
    const float* ea    = (const float*)d_in[2];
    const int*   batch = (const int*)d_in[3];
    const float* W1    = (const float*)d_in[4];
    const float* b1    = (const float*)d_in[5];
    const float* W2    = (const float*)d_in[6];
    const float* b2    = (const float*)d_in[7];
    const float* root  = (const float*)d_in[8];
    const float* cb    = (const float*)d_in[9];
    const float* fcw   = (const float*)d_in[10];
    const float* fcb   = (const float*)d_in[11];
    float* out = (float*)d_out;

    char* w = (char*)d_ws;
    auto alloc = [&](size_t bytes) {
        char* p = w;
        w += (bytes + 255) & ~size_t(255);
        return p;
    };
    ushort* W2T  = (ushort*)alloc((size_t)32 * KW * 2);
    ushort* xh   = (ushort*)alloc((size_t)N_NODES * F_IN * 2);
    __half* aggh = (__half*)alloc((size_t)N_NODES * LATENT * 2);
    float*  pool = (float*)alloc(N_GRAPHS * LATENT * 4);
    float*  pcnt = (float*)alloc(N_GRAPHS * 4);

    prep_kernel<<<1563, 256, 0, stream>>>(x, W2, b2, xh, W2T, (uint4*)aggh, pool, pcnt);
    edge_mfma_kernel<<<N_EBLK, 512, 0, stream>>>(xh, ei, ea, W1, b1, W2T, aggh);
    nodepool_kernel<<<(N_NODES + 8 * VN - 1) / (8 * VN), 256, 0, stream>>>(
        x, aggh, root, cb, batch, pool, pcnt);
    final_kernel<<<(N_GRAPHS * EMBED + 255) / 256, 256, 0, stream>>>(pool, pcnt, fcw, fcb, out);
}